// Round 18
// baseline (29.128 us; speedup 1.0000x reference)
//
#include <hip/hip_runtime.h>

#define AS1 __attribute__((address_space(1)))
#define AS3 __attribute__((address_space(3)))

typedef unsigned short u16;
typedef _Float16 f16;
typedef __bf16 bf16x8 __attribute__((ext_vector_type(8)));
typedef float f32x4 __attribute__((ext_vector_type(4)));
typedef _Float16 f16x8 __attribute__((ext_vector_type(8)));
typedef unsigned short u16x8 __attribute__((ext_vector_type(8)));

// ws layout (20 MB):
//   A: [4][512][1024]  bf16(u16) @ 0     (4 MB)   A[seg][b][i] = b_seg(x[b][i])
//   P: [16][512][1024] f16       @ 4 MB  (16 MB)  split-K partials (f16)
// W is NOT materialized: gemm stages cp f32 directly (saves 24 MB prep traffic).

__device__ __forceinline__ u16 bf(float f) {
    union { __bf16 h; u16 u; } c;
    c.h = (__bf16)f;               // RNE
    return c.u;
}

// A-only prep: 6 MB traffic, 256 blocks.
__global__ __launch_bounds__(256) void prep_kernel(
    const float* __restrict__ x, u16* __restrict__ A)
{
    const int base = blockIdx.x * 2048;
    const int idx = base + threadIdx.x * 8;
    float4 v0 = *(const float4*)(x + idx);
    float4 v1 = *(const float4*)(x + idx + 4);
    float vv[8] = {v0.x, v0.y, v0.z, v0.w, v1.x, v1.y, v1.z, v1.w};
    u16 q[4][8];
    #pragma unroll
    for (int j = 0; j < 8; ++j) {
        float xx = vv[j];
        float t = fminf(fabsf(xx), 1.0f);
        float s = 1.0f - t;
        q[0][j] = bf(s * s * s * xx);
        q[1][j] = bf(3.0f * s * s * t * xx);
        q[2][j] = bf(3.0f * s * t * t * xx);
        q[3][j] = bf(t * t * t * xx);
    }
    #pragma unroll
    for (int seg = 0; seg < 4; ++seg) {
        u16x8 o;
        #pragma unroll
        for (int j = 0; j < 8; ++j) o[j] = q[seg][j];
        *(u16x8*)(A + seg * 524288 + idx) = o;
    }
}

__device__ __forceinline__ void load16(const void* g, void* l) {
    __builtin_amdgcn_global_load_lds((const AS1 unsigned int*)g,
                                     (AS3 unsigned int*)l, 16, 0, 0);
}

// 256x128 tile, BK=64 (4 k-steps of K=256/WG), split-K=16, 512 threads
// (8 waves: 4M x 2N, wave tile 64x64, acc[4][4]).
// A: bf16 from ws, XOR-swizzled (chunk (row,s) <- global (row, s^(row&7))).
// W: f32 DIRECT from cp via global_load_lds, swizzle s^((row&7)<<1) (keeps
// 16B-pair adjacency for 2xb128 frag reads); f32->bf16 cvt at read time.
// Counted-vmcnt (r8 pattern): issue next (8/thread), wait vmcnt(8), barrier,
// compute, barrier. Never vmcnt(0) until tail. LDS 2 x (32+32) KB = 128 KB.
__global__ __launch_bounds__(512) void gemm_kernel(
    const u16* __restrict__ A,
    const float* __restrict__ cp0, const float* __restrict__ cp1,
    const float* __restrict__ cp2, const float* __restrict__ cp3,
    f16* __restrict__ P)
{
    __shared__ u16   lsA[2][256 * 64];   // 32 KB each
    __shared__ float lsW[2][128 * 64];   // 32 KB each

    const int tid  = threadIdx.x;
    const int lane = tid & 63;
    const int wid  = tid >> 6;

    const int bid  = blockIdx.x;          // 0..255
    const int nb   = bid & 7;             // N-block (XCD spread)
    const int kz   = (bid >> 3) & 15;     // K-slice 0..15
    const int mb   = bid >> 7;            // M-block 0..1
    const int seg  = kz >> 2;
    const int kbase = (kz & 3) * 256;
    const int brow = mb * 256;
    const int bcol = nb * 128;

    const float* cps[4] = {cp0, cp1, cp2, cp3};
    const u16*   Ag = A + seg * 524288 + brow * 1024 + kbase;
    const float* Wg = cps[seg] + bcol * 1024 + kbase;

    // A staging: 2048 chunks (256 rows x 8); 4/thread; source pre-swizzled
    int goffA[4], loffA[4];
    #pragma unroll
    for (int j = 0; j < 4; ++j) {
        const int c   = tid + j * 512;
        const int row = c >> 3;
        goffA[j] = row * 1024 + ((c & 7) ^ (row & 7)) * 8;   // bf16 elems
        loffA[j] = c * 8;
    }
    // W staging: 2048 chunks (128 rows x 16 of 4 f32); 4/thread
    int goffW[4], loffW[4];
    #pragma unroll
    for (int j = 0; j < 4; ++j) {
        const int c   = tid + j * 512;
        const int row = c >> 4;
        goffW[j] = row * 1024 + ((c & 15) ^ ((row & 7) << 1)) * 4;  // f32 elems
        loffW[j] = c * 4;
    }

    // wave tile: 4(M) x 2(N); 64x64 each
    const int wr = (wid >> 1) * 64;
    const int wc = (wid & 1) * 64;
    const int fr = lane & 15;
    const int q  = lane >> 4;
    int ofsA[2], sW[2];
    #pragma unroll
    for (int kk = 0; kk < 2; ++kk) {
        ofsA[kk] = ((q + 4 * kk) ^ (fr & 7)) * 16;                 // bytes in row
        sW[kk]   = (((q + 4 * kk) * 2) ^ ((fr & 7) << 1)) * 16;    // bytes in row
    }

    f32x4 acc[4][4] = {};

    // ---- prologue: issue step 0 (8 loads/thread) ----
    #pragma unroll
    for (int j = 0; j < 4; ++j) load16(Ag + goffA[j], &lsA[0][loffA[j]]);
    #pragma unroll
    for (int j = 0; j < 4; ++j) load16(Wg + goffW[j], &lsW[0][loffW[j]]);

    #pragma unroll
    for (int kt = 0; kt < 4; ++kt) {
        const int buf = kt & 1;
        if (kt < 3) {
            const int k0 = (kt + 1) * 64;
            #pragma unroll
            for (int j = 0; j < 4; ++j)
                load16(Ag + k0 + goffA[j], &lsA[buf ^ 1][loffA[j]]);
            #pragma unroll
            for (int j = 0; j < 4; ++j)
                load16(Wg + k0 + goffW[j], &lsW[buf ^ 1][loffW[j]]);
            asm volatile("s_waitcnt vmcnt(8)" ::: "memory");
        } else {
            asm volatile("s_waitcnt vmcnt(0)" ::: "memory");
        }
        __builtin_amdgcn_s_barrier();
        __builtin_amdgcn_sched_barrier(0);     // rule #18

        const char* bA = (const char*)lsA[buf];
        const char* bW = (const char*)lsW[buf];
        #pragma unroll
        for (int kk = 0; kk < 2; ++kk) {
            bf16x8 a[4], b[4];
            #pragma unroll
            for (int m = 0; m < 4; ++m)
                a[m] = *(const bf16x8*)(bA + (wr + m * 16 + fr) * 128 + ofsA[kk]);
            #pragma unroll
            for (int n = 0; n < 4; ++n) {
                const char* rp = bW + (wc + n * 16 + fr) * 256 + sW[kk];
                f32x4 w0 = *(const f32x4*)(rp);
                f32x4 w1 = *(const f32x4*)(rp + 16);
                bf16x8 t;
                t[0] = (__bf16)w0[0]; t[1] = (__bf16)w0[1];
                t[2] = (__bf16)w0[2]; t[3] = (__bf16)w0[3];
                t[4] = (__bf16)w1[0]; t[5] = (__bf16)w1[1];
                t[6] = (__bf16)w1[2]; t[7] = (__bf16)w1[3];
                b[n] = t;
            }
            #pragma unroll
            for (int m = 0; m < 4; ++m)
                #pragma unroll
                for (int n = 0; n < 4; ++n)
                    acc[m][n] = __builtin_amdgcn_mfma_f32_16x16x32_bf16(
                        a[m], b[n], acc[m][n], 0, 0, 0);
        }
        __builtin_amdgcn_s_barrier();          // buf consumed; next DMA safe
        __builtin_amdgcn_sched_barrier(0);
    }

    // ---- epilogue: f16 partials. C/D layout col=lane&15, row=(lane>>4)*4+j ----
    f16* Pk = P + kz * 524288;
    const int cr0 = brow + wr + q * 4;
    const int cc0 = bcol + wc + fr;
    #pragma unroll
    for (int m = 0; m < 4; ++m)
        #pragma unroll
        for (int n = 0; n < 4; ++n)
            #pragma unroll
            for (int j = 0; j < 4; ++j)
                Pk[(cr0 + m * 16 + j) * 1024 + cc0 + n * 16] = (f16)acc[m][n][j];
}

// Fixed-order 16-slice f16 sum -> f32 out (bitwise deterministic).
__global__ __launch_bounds__(256) void reduce_kernel(
    const f16* __restrict__ P, float* __restrict__ out)
{
    const int idx = (blockIdx.x * 256 + threadIdx.x) * 8;
    float s[8] = {};
    #pragma unroll
    for (int z = 0; z < 16; ++z) {
        f16x8 v = *(const f16x8*)(P + z * 524288 + idx);
        #pragma unroll
        for (int e = 0; e < 8; ++e) s[e] += (float)v[e];
    }
    float4 o0, o1;
    o0.x = s[0]; o0.y = s[1]; o0.z = s[2]; o0.w = s[3];
    o1.x = s[4]; o1.y = s[5]; o1.z = s[6]; o1.w = s[7];
    *(float4*)(out + idx)     = o0;
    *(float4*)(out + idx + 4) = o1;
}

extern "C" void kernel_launch(void* const* d_in, const int* in_sizes, int n_in,
                              void* d_out, int out_size, void* d_ws, size_t ws_size,
                              hipStream_t stream)
{
    const float* x   = (const float*)d_in[0];
    const float* cp0 = (const float*)d_in[1];
    const float* cp1 = (const float*)d_in[2];
    const float* cp2 = (const float*)d_in[3];
    const float* cp3 = (const float*)d_in[4];

    u16*   A   = (u16*)d_ws;
    f16*   P   = (f16*)((char*)d_ws + (4u << 20));
    float* out = (float*)d_out;

    prep_kernel<<<256, 256, 0, stream>>>(x, A);
    gemm_kernel<<<256, 512, 0, stream>>>(A, cp0, cp1, cp2, cp3, P);
    reduce_kernel<<<256, 256, 0, stream>>>(P, out);
}

// Round 19
// 23.972 us; speedup vs baseline: 1.2151x; 1.2151x over previous
//
#include <hip/hip_runtime.h>

#define AS1 __attribute__((address_space(1)))
#define AS3 __attribute__((address_space(3)))

typedef unsigned short u16;
typedef _Float16 f16;
typedef __bf16 bf16x8 __attribute__((ext_vector_type(8)));
typedef float f32x4 __attribute__((ext_vector_type(4)));
typedef _Float16 f16x8 __attribute__((ext_vector_type(8)));
typedef unsigned short u16x8 __attribute__((ext_vector_type(8)));

// FINAL (r15 structure, session best 23.74 us):
//   prep: 30 MB stream, x->A (Bernstein bf16) + cp->W (bf16), 16B stores
//   gemm: 128x128 tile, BK=64, split-K=8, 3-deep counted-vmcnt pipeline,
//         XOR-swizzled LDS staged via pre-swizzled-source global_load_lds,
//         2x2 XCD tile grouping, f16 partials
//   reduce: fixed-order 8-slice f16 sum -> f32 (bitwise deterministic)
//
// ws layout (20 MB):
//   A: [4][512][1024]  bf16(u16) @ 0      (4 MB)   A[seg][b][i] = b_seg(x[b][i])
//   W: [4][1024][1024] bf16(u16) @ 4 MB   (8 MB)   W[seg][o][i] = bf16(cp_seg[o][i])
//   P: [8][512][1024]  f16       @ 12 MB  (8 MB)   split-K partials (f16)

__device__ __forceinline__ u16 bf(float f) {
    union { __bf16 h; u16 u; } c;
    c.h = (__bf16)f;               // RNE
    return c.u;
}

// Streaming-clean prep: one block = one contiguous chunk of ONE source stream.
__global__ __launch_bounds__(256) void prep_kernel(
    const float* __restrict__ x,
    const float* __restrict__ cp0, const float* __restrict__ cp1,
    const float* __restrict__ cp2, const float* __restrict__ cp3,
    u16* __restrict__ A, u16* __restrict__ W)
{
    const int bid = blockIdx.x;
    const int tid = threadIdx.x;
    if (bid < 512) {
        const int seg  = bid >> 7;
        const int base = (bid & 127) * 8192;
        const float* cps[4] = {cp0, cp1, cp2, cp3};
        const float* src = cps[seg] + base;
        u16* dst = W + seg * 1048576 + base;
        #pragma unroll
        for (int it = 0; it < 4; ++it) {
            const int e = it * 2048 + tid * 8;
            float4 v0 = *(const float4*)(src + e);
            float4 v1 = *(const float4*)(src + e + 4);
            u16x8 o;
            o[0] = bf(v0.x); o[1] = bf(v0.y); o[2] = bf(v0.z); o[3] = bf(v0.w);
            o[4] = bf(v1.x); o[5] = bf(v1.y); o[6] = bf(v1.z); o[7] = bf(v1.w);
            *(u16x8*)(dst + e) = o;
        }
    } else {
        const int base = (bid - 512) * 4096;
        #pragma unroll
        for (int it = 0; it < 2; ++it) {
            const int idx = base + it * 2048 + tid * 8;
            float4 v0 = *(const float4*)(x + idx);
            float4 v1 = *(const float4*)(x + idx + 4);
            float vv[8] = {v0.x, v0.y, v0.z, v0.w, v1.x, v1.y, v1.z, v1.w};
            u16 q[4][8];
            #pragma unroll
            for (int j = 0; j < 8; ++j) {
                float xx = vv[j];
                float t = fminf(fabsf(xx), 1.0f);
                float s = 1.0f - t;
                q[0][j] = bf(s * s * s * xx);
                q[1][j] = bf(3.0f * s * s * t * xx);
                q[2][j] = bf(3.0f * s * t * t * xx);
                q[3][j] = bf(t * t * t * xx);
            }
            #pragma unroll
            for (int seg = 0; seg < 4; ++seg) {
                u16x8 o;
                #pragma unroll
                for (int j = 0; j < 8; ++j) o[j] = q[seg][j];
                *(u16x8*)(A + seg * 524288 + idx) = o;
            }
        }
    }
}

__device__ __forceinline__ void load16(const u16* g, u16* l) {
    __builtin_amdgcn_global_load_lds((const AS1 unsigned int*)g,
                                     (AS3 unsigned int*)l, 16, 0, 0);
}

// 128x128 tile, BK=64, 8 k-steps, split-K=8, 512 threads (8 waves of 64x32).
// 3-DEEP pipeline, ONE barrier per step: DMA for tile t+2 issued at step t;
// per-wave s_waitcnt vmcnt(4) retires only its own tile-t loads; queue never
// drains until the tail (T3/T4). LDS 3 bufs x (16+16) KB = 96 KB.
// XOR swizzle: chunk (row,s) holds global (row, s^(row&7)); pre-swizzled
// source, linear LDS dest (rule #21).
__global__ __launch_bounds__(512) void gemm_kernel(
    const u16* __restrict__ A, const u16* __restrict__ W,
    f16* __restrict__ P)
{
    __shared__ u16 lsA[3][128 * 64];
    __shared__ u16 lsB[3][128 * 64];

    const int tid  = threadIdx.x;
    const int lane = tid & 63;
    const int wid  = tid >> 6;

    const int bid  = blockIdx.x;          // 0..255
    const int grp  = bid & 7;             // XCD group = (mb>>1)*4 + (nb>>1)
    const int sub  = bid >> 3;            // 0..31 within group
    const int mb   = (grp >> 2) * 2 + (sub & 1);
    const int nb   = (grp & 3) * 2 + ((sub >> 1) & 1);
    const int kz   = sub >> 2;            // 0..7
    const int seg  = kz >> 1;
    const int kbase = (kz & 1) * 512;
    const int brow = mb * 128;
    const int bcol = nb * 128;

    const u16* Ag = A + seg * 524288  + brow * 1024 + kbase;
    const u16* Wg = W + seg * 1048576 + bcol * 1024 + kbase;

    // staging: 1024 chunks of 16B per tile (128 rows x 8 chunks); 2/thread/matrix
    int goff[2], loff[2];
    #pragma unroll
    for (int j = 0; j < 2; ++j) {
        const int c   = tid + j * 512;
        const int row = c >> 3;
        goff[j] = row * 1024 + ((c & 7) ^ (row & 7)) * 8;
        loff[j] = c * 8;
    }

    // wave sub-tile: 2(M) x 4(N); each wave 64x32
    const int wr = (wid >> 2) * 64;
    const int wc = (wid & 3) * 32;
    const int fr = lane & 15;
    const int q  = lane >> 4;
    int ofs[2];
    ofs[0] = ((q    ) ^ (lane & 7)) * 16;
    ofs[1] = ((q + 4) ^ (lane & 7)) * 16;

    f32x4 acc[4][2] = {};

    // ---- prologue: issue tiles 0,1 (8 loads/thread outstanding) ----
    #pragma unroll
    for (int j = 0; j < 2; ++j) {
        load16(Ag + goff[j],      &lsA[0][loff[j]]);
        load16(Wg + goff[j],      &lsB[0][loff[j]]);
    }
    #pragma unroll
    for (int j = 0; j < 2; ++j) {
        load16(Ag + 64 + goff[j], &lsA[1][loff[j]]);
        load16(Wg + 64 + goff[j], &lsB[1][loff[j]]);
    }

    #pragma unroll
    for (int kt = 0; kt < 8; ++kt) {
        const int buf = kt % 3;
        // own tile-kt loads retired (oldest 4); tile kt+1's 4 stay in flight
        if (kt < 7) {
            asm volatile("s_waitcnt vmcnt(4)" ::: "memory");
        } else {
            asm volatile("s_waitcnt vmcnt(0)" ::: "memory");
        }
        __builtin_amdgcn_s_barrier();          // all waves: buf ready, and all
        __builtin_amdgcn_sched_barrier(0);     // finished step kt-1 (rule #18)

        if (kt < 6) {
            const int k0 = (kt + 2) * 64;
            const int nbuf = (kt + 2) % 3;     // == buf consumed at step kt-1
            #pragma unroll
            for (int j = 0; j < 2; ++j) {
                load16(Ag + k0 + goff[j], &lsA[nbuf][loff[j]]);
                load16(Wg + k0 + goff[j], &lsB[nbuf][loff[j]]);
            }
        }

        const char* bA = (const char*)lsA[buf];
        const char* bB = (const char*)lsB[buf];
        #pragma unroll
        for (int kk = 0; kk < 2; ++kk) {
            bf16x8 a[4], b[2];
            #pragma unroll
            for (int m = 0; m < 4; ++m)
                a[m] = *(const bf16x8*)(bA + (wr + m * 16 + fr) * 128 + ofs[kk]);
            #pragma unroll
            for (int n = 0; n < 2; ++n)
                b[n] = *(const bf16x8*)(bB + (wc + n * 16 + fr) * 128 + ofs[kk]);
            #pragma unroll
            for (int m = 0; m < 4; ++m)
                #pragma unroll
                for (int n = 0; n < 2; ++n)
                    acc[m][n] = __builtin_amdgcn_mfma_f32_16x16x32_bf16(
                        a[m], b[n], acc[m][n], 0, 0, 0);
        }
    }

    // ---- epilogue: f16 partials. C/D layout col=lane&15, row=(lane>>4)*4+j ----
    f16* Pk = P + kz * 524288;
    const int cr0 = brow + wr + q * 4;
    const int cc0 = bcol + wc + fr;
    #pragma unroll
    for (int m = 0; m < 4; ++m)
        #pragma unroll
        for (int n = 0; n < 2; ++n)
            #pragma unroll
            for (int j = 0; j < 4; ++j)
                Pk[(cr0 + m * 16 + j) * 1024 + cc0 + n * 16] = (f16)acc[m][n][j];
}

// Fixed-order 8-slice f16 sum -> f32 (bitwise deterministic).
__global__ __launch_bounds__(256) void reduce_kernel(
    const f16* __restrict__ P, float* __restrict__ out)
{
    const int idx = (blockIdx.x * 256 + threadIdx.x) * 8;
    float s[8] = {};
    #pragma unroll
    for (int z = 0; z < 8; ++z) {
        f16x8 v = *(const f16x8*)(P + z * 524288 + idx);
        #pragma unroll
        for (int e = 0; e < 8; ++e) s[e] += (float)v[e];
    }
    float4 o0, o1;
    o0.x = s[0]; o0.y = s[1]; o0.z = s[2]; o0.w = s[3];
    o1.x = s[4]; o1.y = s[5]; o1.z = s[6]; o1.w = s[7];
    *(float4*)(out + idx)     = o0;
    *(float4*)(out + idx + 4) = o1;
}

extern "C" void kernel_launch(void* const* d_in, const int* in_sizes, int n_in,
                              void* d_out, int out_size, void* d_ws, size_t ws_size,
                              hipStream_t stream)
{
    const float* x   = (const float*)d_in[0];
    const float* cp0 = (const float*)d_in[1];
    const float* cp1 = (const float*)d_in[2];
    const float* cp2 = (const float*)d_in[3];
    const float* cp3 = (const float*)d_in[4];

    u16*   A   = (u16*)d_ws;
    u16*   Wb  = (u16*)((char*)d_ws + (4u << 20));
    f16*   P   = (f16*)((char*)d_ws + (12u << 20));
    float* out = (float*)d_out;

    prep_kernel<<<640, 256, 0, stream>>>(x, cp0, cp1, cp2, cp3, A, Wb);
    gemm_kernel<<<256, 512, 0, stream>>>(A, Wb, P);
    reduce_kernel<<<256, 256, 0, stream>>>(P, out);
}

// Round 20
// 23.636 us; speedup vs baseline: 1.2323x; 1.0142x over previous
//
#include <hip/hip_runtime.h>

#define AS1 __attribute__((address_space(1)))
#define AS3 __attribute__((address_space(3)))

typedef unsigned short u16;
typedef _Float16 f16;
typedef __bf16 bf16x8 __attribute__((ext_vector_type(8)));
typedef float f32x4 __attribute__((ext_vector_type(4)));
typedef _Float16 f16x8 __attribute__((ext_vector_type(8)));
typedef unsigned short u16x8 __attribute__((ext_vector_type(8)));

// r15 structure (session best) + two final micro-levers:
//   (1) s_setprio(1) around MFMA cluster (T5; schedule is counted-vmcnt
//       phase-split -> waves have role diversity per SIMD)
//   (2) prep rebalanced to exactly 768 = 3x256 blocks, W/A interleaved bid%3
//
// ws layout (20 MB):
//   A: [4][512][1024]  bf16(u16) @ 0      (4 MB)   A[seg][b][i] = b_seg(x[b][i])
//   W: [4][1024][1024] bf16(u16) @ 4 MB   (8 MB)   W[seg][o][i] = bf16(cp_seg[o][i])
//   P: [8][512][1024]  f16       @ 12 MB  (8 MB)   split-K partials (f16)

__device__ __forceinline__ u16 bf(float f) {
    union { __bf16 h; u16 u; } c;
    c.h = (__bf16)f;               // RNE
    return c.u;
}

// 768 blocks = exactly 3 per CU; type interleaved: bid%3 in {0,1} -> W chunk,
// bid%3 == 2 -> A chunk. All accesses contiguous 16B per lane.
__global__ __launch_bounds__(256) void prep_kernel(
    const float* __restrict__ x,
    const float* __restrict__ cp0, const float* __restrict__ cp1,
    const float* __restrict__ cp2, const float* __restrict__ cp3,
    u16* __restrict__ A, u16* __restrict__ W)
{
    const int bid = blockIdx.x;
    const int tid = threadIdx.x;
    const int ty  = bid % 3;
    if (ty < 2) {
        // W: widx in [0,512): 8192-elem contiguous chunk of one cp
        const int widx = (bid / 3) * 2 + ty;
        const int seg  = widx >> 7;
        const int base = (widx & 127) * 8192;
        const float* cps[4] = {cp0, cp1, cp2, cp3};
        const float* src = cps[seg] + base;
        u16* dst = W + seg * 1048576 + base;
        #pragma unroll
        for (int it = 0; it < 4; ++it) {
            const int e = it * 2048 + tid * 8;
            float4 v0 = *(const float4*)(src + e);
            float4 v1 = *(const float4*)(src + e + 4);
            u16x8 o;
            o[0] = bf(v0.x); o[1] = bf(v0.y); o[2] = bf(v0.z); o[3] = bf(v0.w);
            o[4] = bf(v1.x); o[5] = bf(v1.y); o[6] = bf(v1.z); o[7] = bf(v1.w);
            *(u16x8*)(dst + e) = o;
        }
    } else {
        // A: aidx in [0,256): 2048-elem chunk of x -> 4 Bernstein segments
        const int idx = (bid / 3) * 2048 + tid * 8;
        float4 v0 = *(const float4*)(x + idx);
        float4 v1 = *(const float4*)(x + idx + 4);
        float vv[8] = {v0.x, v0.y, v0.z, v0.w, v1.x, v1.y, v1.z, v1.w};
        u16 q[4][8];
        #pragma unroll
        for (int j = 0; j < 8; ++j) {
            float xx = vv[j];
            float t = fminf(fabsf(xx), 1.0f);
            float s = 1.0f - t;
            q[0][j] = bf(s * s * s * xx);
            q[1][j] = bf(3.0f * s * s * t * xx);
            q[2][j] = bf(3.0f * s * t * t * xx);
            q[3][j] = bf(t * t * t * xx);
        }
        #pragma unroll
        for (int seg = 0; seg < 4; ++seg) {
            u16x8 o;
            #pragma unroll
            for (int j = 0; j < 8; ++j) o[j] = q[seg][j];
            *(u16x8*)(A + seg * 524288 + idx) = o;
        }
    }
}

__device__ __forceinline__ void load16(const u16* g, u16* l) {
    __builtin_amdgcn_global_load_lds((const AS1 unsigned int*)g,
                                     (AS3 unsigned int*)l, 16, 0, 0);
}

// 128x128 tile, BK=64, 8 k-steps, split-K=8, 512 threads (8 waves of 64x32).
// 3-DEEP pipeline, ONE barrier per step: DMA for tile t+2 issued at step t;
// per-wave s_waitcnt vmcnt(4) retires only its own tile-t loads; queue never
// drains until the tail (T3/T4). setprio(1) wraps the MFMA cluster (T5).
// LDS 3 bufs x (16+16) KB = 96 KB. XOR swizzle: chunk (row,s) holds global
// (row, s^(row&7)); pre-swizzled source, linear LDS dest (rule #21).
__global__ __launch_bounds__(512) void gemm_kernel(
    const u16* __restrict__ A, const u16* __restrict__ W,
    f16* __restrict__ P)
{
    __shared__ u16 lsA[3][128 * 64];
    __shared__ u16 lsB[3][128 * 64];

    const int tid  = threadIdx.x;
    const int lane = tid & 63;
    const int wid  = tid >> 6;

    const int bid  = blockIdx.x;          // 0..255
    const int grp  = bid & 7;             // XCD group = (mb>>1)*4 + (nb>>1)
    const int sub  = bid >> 3;            // 0..31 within group
    const int mb   = (grp >> 2) * 2 + (sub & 1);
    const int nb   = (grp & 3) * 2 + ((sub >> 1) & 1);
    const int kz   = sub >> 2;            // 0..7
    const int seg  = kz >> 1;
    const int kbase = (kz & 1) * 512;
    const int brow = mb * 128;
    const int bcol = nb * 128;

    const u16* Ag = A + seg * 524288  + brow * 1024 + kbase;
    const u16* Wg = W + seg * 1048576 + bcol * 1024 + kbase;

    // staging: 1024 chunks of 16B per tile (128 rows x 8 chunks); 2/thread/matrix
    int goff[2], loff[2];
    #pragma unroll
    for (int j = 0; j < 2; ++j) {
        const int c   = tid + j * 512;
        const int row = c >> 3;
        goff[j] = row * 1024 + ((c & 7) ^ (row & 7)) * 8;
        loff[j] = c * 8;
    }

    // wave sub-tile: 2(M) x 4(N); each wave 64x32
    const int wr = (wid >> 2) * 64;
    const int wc = (wid & 3) * 32;
    const int fr = lane & 15;
    const int q  = lane >> 4;
    int ofs[2];
    ofs[0] = ((q    ) ^ (lane & 7)) * 16;
    ofs[1] = ((q + 4) ^ (lane & 7)) * 16;

    f32x4 acc[4][2] = {};

    // ---- prologue: issue tiles 0,1 (8 loads/thread outstanding) ----
    #pragma unroll
    for (int j = 0; j < 2; ++j) {
        load16(Ag + goff[j],      &lsA[0][loff[j]]);
        load16(Wg + goff[j],      &lsB[0][loff[j]]);
    }
    #pragma unroll
    for (int j = 0; j < 2; ++j) {
        load16(Ag + 64 + goff[j], &lsA[1][loff[j]]);
        load16(Wg + 64 + goff[j], &lsB[1][loff[j]]);
    }

    #pragma unroll
    for (int kt = 0; kt < 8; ++kt) {
        const int buf = kt % 3;
        // own tile-kt loads retired (oldest 4); tile kt+1's 4 stay in flight
        if (kt < 7) {
            asm volatile("s_waitcnt vmcnt(4)" ::: "memory");
        } else {
            asm volatile("s_waitcnt vmcnt(0)" ::: "memory");
        }
        __builtin_amdgcn_s_barrier();          // all waves: buf ready, and all
        __builtin_amdgcn_sched_barrier(0);     // finished step kt-1 (rule #18)

        if (kt < 6) {
            const int k0 = (kt + 2) * 64;
            const int nbuf = (kt + 2) % 3;     // == buf consumed at step kt-1
            #pragma unroll
            for (int j = 0; j < 2; ++j) {
                load16(Ag + k0 + goff[j], &lsA[nbuf][loff[j]]);
                load16(Wg + k0 + goff[j], &lsB[nbuf][loff[j]]);
            }
        }

        const char* bA = (const char*)lsA[buf];
        const char* bB = (const char*)lsB[buf];
        #pragma unroll
        for (int kk = 0; kk < 2; ++kk) {
            bf16x8 a[4], b[2];
            #pragma unroll
            for (int m = 0; m < 4; ++m)
                a[m] = *(const bf16x8*)(bA + (wr + m * 16 + fr) * 128 + ofs[kk]);
            #pragma unroll
            for (int n = 0; n < 2; ++n)
                b[n] = *(const bf16x8*)(bB + (wc + n * 16 + fr) * 128 + ofs[kk]);
            __builtin_amdgcn_s_setprio(1);     // T5: favor MFMA-entering wave
            #pragma unroll
            for (int m = 0; m < 4; ++m)
                #pragma unroll
                for (int n = 0; n < 2; ++n)
                    acc[m][n] = __builtin_amdgcn_mfma_f32_16x16x32_bf16(
                        a[m], b[n], acc[m][n], 0, 0, 0);
            __builtin_amdgcn_s_setprio(0);
        }
    }

    // ---- epilogue: f16 partials. C/D layout col=lane&15, row=(lane>>4)*4+j ----
    f16* Pk = P + kz * 524288;
    const int cr0 = brow + wr + q * 4;
    const int cc0 = bcol + wc + fr;
    #pragma unroll
    for (int m = 0; m < 4; ++m)
        #pragma unroll
        for (int n = 0; n < 2; ++n)
            #pragma unroll
            for (int j = 0; j < 4; ++j)
                Pk[(cr0 + m * 16 + j) * 1024 + cc0 + n * 16] = (f16)acc[m][n][j];
}

// Fixed-order 8-slice f16 sum -> f32 (bitwise deterministic).
__global__ __launch_bounds__(256) void reduce_kernel(
    const f16* __restrict__ P, float* __restrict__ out)
{
    const int idx = (blockIdx.x * 256 + threadIdx.x) * 8;
    float s[8] = {};
    #pragma unroll
    for (int z = 0; z < 8; ++z) {
        f16x8 v = *(const f16x8*)(P + z * 524288 + idx);
        #pragma unroll
        for (int e = 0; e < 8; ++e) s[e] += (float)v[e];
    }
    float4 o0, o1;
    o0.x = s[0]; o0.y = s[1]; o0.z = s[2]; o0.w = s[3];
    o1.x = s[4]; o1.y = s[5]; o1.z = s[6]; o1.w = s[7];
    *(float4*)(out + idx)     = o0;
    *(float4*)(out + idx + 4) = o1;
}

extern "C" void kernel_launch(void* const* d_in, const int* in_sizes, int n_in,
                              void* d_out, int out_size, void* d_ws, size_t ws_size,
                              hipStream_t stream)
{
    const float* x   = (const float*)d_in[0];
    const float* cp0 = (const float*)d_in[1];
    const float* cp1 = (const float*)d_in[2];
    const float* cp2 = (const float*)d_in[3];
    const float* cp3 = (const float*)d_in[4];

    u16*   A   = (u16*)d_ws;
    u16*   Wb  = (u16*)((char*)d_ws + (4u << 20));
    f16*   P   = (f16*)((char*)d_ws + (12u << 20));
    float* out = (float*)d_out;

    prep_kernel<<<768, 256, 0, stream>>>(x, cp0, cp1, cp2, cp3, A, Wb);
    gemm_kernel<<<256, 512, 0, stream>>>(A, Wb, P);
    reduce_kernel<<<256, 256, 0, stream>>>(P, out);
}